// Round 20
// baseline (797.644 us; speedup 1.0000x reference)
//
#include <hip/hip_runtime.h>
#include <math.h>

#define TB    720
#define NI    16
#define NH    128
#define NG    512
#define PRED  96
#define CHUNK 90          // 720 = 8 * 90

typedef _Float16 h2    __attribute__((ext_vector_type(2)));
typedef _Float16 f16x4 __attribute__((ext_vector_type(4)));
typedef _Float16 f16x8 __attribute__((ext_vector_type(8)));
typedef float    f32x4 __attribute__((ext_vector_type(4)));

#define LOG2E  1.4426950408889634f
#define LOG2E2 2.8853900817779268f

__device__ __forceinline__ float rcpf_(float v) {
#if __has_builtin(__builtin_amdgcn_rcpf)
    return __builtin_amdgcn_rcpf(v);
#else
    return 1.0f / v;
#endif
}
__device__ __forceinline__ float ex2(float v) {
#if __has_builtin(__builtin_amdgcn_exp2f)
    return __builtin_amdgcn_exp2f(v);
#else
    return exp2f(v);
#endif
}

__device__ __forceinline__ unsigned int packf16(float a, float b) {
    h2 p; p.x = (_Float16)a; p.y = (_Float16)b;
    return __builtin_bit_cast(unsigned int, p);
}
__device__ __forceinline__ f32x4 MFMA(f16x8 a, f16x8 b, f32x4 c) {
    return __builtin_amdgcn_mfma_f32_16x16x32_f16(a, b, c, 0, 0, 0);
}
// A/B frag split-half k layout (verified R9-R19); scaled variant for exp2 gates
__device__ __forceinline__ f16x8 mk8s(const float* p, float s) {
    f16x8 v;
    v[0] = (_Float16)(p[0]  * s); v[1] = (_Float16)(p[1]  * s);
    v[2] = (_Float16)(p[2]  * s); v[3] = (_Float16)(p[3]  * s);
    v[4] = (_Float16)(p[16] * s); v[5] = (_Float16)(p[17] * s);
    v[6] = (_Float16)(p[18] * s); v[7] = (_Float16)(p[19] * s);
    return v;
}
// block LLVM from hoisting loop-invariant LDS reads (hoist->spill hazard, R10/R11-proven)
__device__ __forceinline__ int opaque(int v) { asm volatile("" : "+v"(v)); return v; }

// prescaled-gate LSTM cell: C = [log2e*i, log2e*f, 2log2e*g, log2e*o]
#define CELLBODY(CV, CS, HWPTR, CWBV) { \
    float ei_ = ex2(-(CV)[0]), ef_ = ex2(-(CV)[1]); \
    float eg_ = ex2((CV)[2]),  eo_ = ex2(-(CV)[3]); \
    float di_ = 1.f + ei_, df_ = 1.f + ef_, dg_ = 1.f + eg_, dq_ = 1.f + eo_; \
    float r1_ = rcpf_(di_ * df_), r2_ = rcpf_(dq_ * dg_); \
    float si_ = r1_ * df_, sf_ = r1_ * di_, so_ = r2_ * dg_; \
    float tg_ = __builtin_fmaf(-2.f * r2_, dq_, 1.f); \
    (CS) = sf_ * (CS) + si_ * tg_; \
    float ec_ = ex2((CS) * LOG2E2); \
    float th_ = __builtin_fmaf(-2.f, rcpf_(1.f + ec_), 1.f); \
    float hv_ = so_ * th_; \
    *(_Float16*)((char*)(HWPTR) + (CWBV)) = (_Float16)hv_; }

// ---------------- encoder (R18, unchanged: ~540 us) ----------------
__global__ __launch_bounds__(1024, 4)
void enc_kernel(const float* __restrict__ x,
                const float* __restrict__ Wih_f, const float* __restrict__ Whh_f, const float* __restrict__ b_f,
                const float* __restrict__ Wih_b, const float* __restrict__ Whh_b, const float* __restrict__ b_b,
                float* __restrict__ st)   // st[b][dir][{h,c}][NH]
{
    __shared__ _Float16 hbuf0[16 * NH];        // 4KB frag-major
    __shared__ _Float16 hbuf1[16 * NH];
    __shared__ unsigned int xsh[CHUNK * 128];  // 46KB

    const int blk = blockIdx.x;
    const int dir = blk & 1;
    const int b0  = (blk >> 1) << 4;
    const int t   = threadIdx.x;
    const int wv  = t >> 6;      // 0..15
    const int l   = t & 63;
    const int lr  = l & 15;
    const int lk  = l >> 4;

    const float* Wih = dir ? Wih_b : Wih_f;
    const float* Whh = dir ? Whh_b : Whh_f;
    const float* bv  = dir ? b_b   : b_f;

    const int mt0 = 2 * wv, mt1 = 2 * wv + 1;
    const int R0 = mt0 * 16 + lr, R1 = mt1 * 16 + lr;
    const int or0 = (R0 & 3) * 128 + (R0 >> 2);
    const int or1 = (R1 & 3) * 128 + (R1 >> 2);
    const float s0 = ((or0 >> 7) == 2) ? LOG2E2 : LOG2E;
    const float s1 = ((or1 >> 7) == 2) ? LOG2E2 : LOG2E;
    const float* p0 = Whh + (size_t)or0 * NH + lk * 4;
    const float* p1 = Whh + (size_t)or1 * NH + lk * 4;
    f16x8 w0_0 = mk8s(p0, s0), w0_1 = mk8s(p0 + 32, s0), w0_2 = mk8s(p0 + 64, s0), w0_3 = mk8s(p0 + 96, s0);
    f16x8 w1_0 = mk8s(p1, s1), w1_1 = mk8s(p1 + 32, s1), w1_2 = mk8s(p1 + 64, s1), w1_3 = mk8s(p1 + 96, s1);

    f16x8 ax0, ax1;
#define MKAXR(DST, OR, SC) { \
    const float* xr_ = Wih + (size_t)(OR) * NI + lk * 4; \
    DST[0] = (_Float16)(xr_[0] * (SC)); DST[1] = (_Float16)(xr_[1] * (SC)); \
    DST[2] = (_Float16)(xr_[2] * (SC)); DST[3] = (_Float16)(xr_[3] * (SC)); \
    DST[4] = (_Float16)(bv[(OR)] * (SC)); \
    DST[5] = (_Float16)0.f; DST[6] = (_Float16)0.f; DST[7] = (_Float16)0.f; }
    MKAXR(ax0, or0, s0) MKAXR(ax1, or1, s1)
#undef MKAXR

    const int d0 = mt0 * 4 + lk, d1 = mt1 * 4 + lk;

    ((unsigned int*)hbuf0)[t] = 0u;
    float cs0 = 0.f, cs1 = 0.f;

    const int hro0 = 0 * 1024 + lk * 256 + lr * 16;
    const int hro1 = 1 * 1024 + lk * 256 + lr * 16;
    const int hro2 = 2 * 1024 + lk * 256 + lr * 16;
    const int hro3 = 3 * 1024 + lk * 256 + lr * 16;
#define CWB(D) ((((D) >> 5) * 1024) + ((((D) & 15) >> 2) * 256) + lr * 16 + (((((D) & 31) >> 4) * 4 + ((D) & 3)) * 2))
    const int cwb0 = CWB(d0), cwb1 = CWB(d1);
#undef CWB
    const int xoff = lk * 128 + lr * 8;
    const unsigned int oneku = (lk == 0) ? 0x00003c00u : 0u;  // f16 1.0 -> bx elem4
    const f32x4 CZ = {0.f, 0.f, 0.f, 0.f};
    __syncthreads();

#define STEP(HR, HW, SI) { \
    const char* hrb_ = (const char*)(HR); \
    f16x8 bx; \
    { uint2 xq_ = *(const uint2*)((const char*)xsh + (SI) * 512 + xoff); \
      ((unsigned int*)&bx)[0] = xq_.x; ((unsigned int*)&bx)[1] = xq_.y; \
      ((unsigned int*)&bx)[2] = oneku; ((unsigned int*)&bx)[3] = 0u; } \
    f32x4 C0 = MFMA(ax0, bx, CZ); \
    f32x4 C1 = MFMA(ax1, bx, CZ); \
    f16x8 bh_; \
    bh_ = *(const f16x8*)(hrb_ + hro0); \
    C0 = MFMA(w0_0, bh_, C0); C1 = MFMA(w1_0, bh_, C1); \
    bh_ = *(const f16x8*)(hrb_ + hro1); \
    C0 = MFMA(w0_1, bh_, C0); C1 = MFMA(w1_1, bh_, C1); \
    bh_ = *(const f16x8*)(hrb_ + hro2); \
    C0 = MFMA(w0_2, bh_, C0); C1 = MFMA(w1_2, bh_, C1); \
    bh_ = *(const f16x8*)(hrb_ + hro3); \
    C0 = MFMA(w0_3, bh_, C0); C1 = MFMA(w1_3, bh_, C1); \
    CELLBODY(C0, cs0, HW, cwb0) \
    CELLBODY(C1, cs1, HW, cwb1) \
    __syncthreads(); }

    for (int c = 0; c < 8; ++c) {
        {
            const int c0 = c * CHUNK;
            for (int i = t; i < 16 * CHUNK * 8; i += 1024) {
                const int br  = i / (CHUNK * 8);
                const int rem = i - br * (CHUNK * 8);
                const int ti  = rem >> 3;
                const int dw  = rem & 7;
                const int s_  = c0 + ti;
                const int tt  = dir ? (TB - 1 - s_) : s_;
                float2 v = *(const float2*)(x + ((size_t)(b0 + br) * TB + tt) * NI + dw * 2);
                xsh[ti * 128 + (dw >> 1) * 32 + br * 2 + (dw & 1)] = packf16(v.x, v.y);
            }
        }
        __syncthreads();
        for (int si2 = 0; si2 < CHUNK / 2; ++si2) {
            STEP(hbuf0, hbuf1, si2 * 2)
            STEP(hbuf1, hbuf0, si2 * 2 + 1)
        }
    }
#undef STEP

    {
        const size_t base = ((size_t)(b0 + lr) * 2 + dir) * 2 * NH;
#define CWB(D) ((((D) >> 5) * 1024) + ((((D) & 15) >> 2) * 256) + lr * 16 + (((((D) & 31) >> 4) * 4 + ((D) & 3)) * 2))
        st[base + d0]      = (float)*(const _Float16*)((const char*)hbuf0 + CWB(d0));
        st[base + NH + d0] = cs0;
        st[base + d1]      = (float)*(const _Float16*)((const char*)hbuf0 + CWB(d1));
        st[base + NH + d1] = cs1;
#undef CWB
    }
}

// ---------------- decoder (MFMA, pipelined: P3 overlapped with next-step h-MFMAs) ----------------
// R19's structure (5 LDS reads/thread, 16 blocks) but software-pipelined:
// phase A: C = MFMA(ax, bx(inp_s), Ch) + CELL -> h_{s+1}; barrier.
// phase B: all waves CHCOMP Ch' = sum wh*bh(h_{s+1})  ||  wave0 P3 -> out_s, inp_{s+1}; barrier.
// R19's wave0-serial P3 between barriers (15 waves idle) was the 4875cyc/step cost.
__global__ __launch_bounds__(1024, 4)
void dec_kernel(const float* __restrict__ x,
                const float* __restrict__ Wih_f, const float* __restrict__ Whh_f, const float* __restrict__ b_f,
                const float* __restrict__ Wih_b, const float* __restrict__ Whh_b, const float* __restrict__ b_b,
                const float* __restrict__ Wlin, const float* __restrict__ blin,
                const float* __restrict__ st, float* __restrict__ out)
{
    __shared__ _Float16 hF0[16 * NH], hF1[16 * NH];   // 4KB each, frag-major
    __shared__ _Float16 hB0[16 * NH], hB1[16 * NH];
    __shared__ unsigned int wlin_s[8 * 64 * 4];       // 8KB: Wlin' frag-major [f][lane]
    __shared__ unsigned int inpH[16 * 8];             // 512B: inp f16 [batch][8dw]
    __shared__ float obuf[PRED * 16 * 16];            // 96KB: [s][j][batch]

    const int b0   = blockIdx.x << 4;    // 16 batch per block
    const int t    = threadIdx.x;
    const int wv   = t >> 6;
    const int cell = wv >> 3;            // 0=f, 1=b
    const int wvv  = wv & 7;
    const int l    = t & 63;
    const int lr   = l & 15;
    const int lk   = l >> 4;

    const float* Wih = cell ? Wih_b : Wih_f;
    const float* Whh = cell ? Whh_b : Whh_f;
    const float* bv  = cell ? b_b   : b_f;

    // stage Wlin' frag-major: entry (f, lane): row lr, k = f*32 + lk*4 + {0..3, 16..19}
    if (t < 512) {
        const int f = t >> 6, ll = t & 63;
        const int elr = ll & 15, elk = ll >> 4;
        const float* wr = Wlin + elr * 256 + f * 32 + elk * 4;
        uint4 q;
        q.x = packf16(wr[0],  wr[1]);  q.y = packf16(wr[2],  wr[3]);
        q.z = packf16(wr[16], wr[17]); q.w = packf16(wr[18], wr[19]);
        *(uint4*)&wlin_s[(f * 64 + ll) * 4] = q;
    }

    // ---- static weight frags: 4 m-tiles ----
    const int mt0 = 4 * wvv, mt1 = 4 * wvv + 1, mt2 = 4 * wvv + 2, mt3 = 4 * wvv + 3;
    const int R0 = mt0 * 16 + lr, R1 = mt1 * 16 + lr, R2 = mt2 * 16 + lr, R3 = mt3 * 16 + lr;
    const int or0 = (R0 & 3) * 128 + (R0 >> 2);
    const int or1 = (R1 & 3) * 128 + (R1 >> 2);
    const int or2 = (R2 & 3) * 128 + (R2 >> 2);
    const int or3 = (R3 & 3) * 128 + (R3 >> 2);
    const float s0 = ((or0 >> 7) == 2) ? LOG2E2 : LOG2E;
    const float s1 = ((or1 >> 7) == 2) ? LOG2E2 : LOG2E;
    const float s2 = ((or2 >> 7) == 2) ? LOG2E2 : LOG2E;
    const float s3 = ((or3 >> 7) == 2) ? LOG2E2 : LOG2E;
    const float* p0 = Whh + (size_t)or0 * NH + lk * 4;
    const float* p1 = Whh + (size_t)or1 * NH + lk * 4;
    const float* p2 = Whh + (size_t)or2 * NH + lk * 4;
    const float* p3 = Whh + (size_t)or3 * NH + lk * 4;
    f16x8 w0_0 = mk8s(p0, s0), w0_1 = mk8s(p0 + 32, s0), w0_2 = mk8s(p0 + 64, s0), w0_3 = mk8s(p0 + 96, s0);
    f16x8 w1_0 = mk8s(p1, s1), w1_1 = mk8s(p1 + 32, s1), w1_2 = mk8s(p1 + 64, s1), w1_3 = mk8s(p1 + 96, s1);
    f16x8 w2_0 = mk8s(p2, s2), w2_1 = mk8s(p2 + 32, s2), w2_2 = mk8s(p2 + 64, s2), w2_3 = mk8s(p2 + 96, s2);
    f16x8 w3_0 = mk8s(p3, s3), w3_1 = mk8s(p3 + 32, s3), w3_2 = mk8s(p3 + 64, s3), w3_3 = mk8s(p3 + 96, s3);

    f16x8 ax0, ax1, ax2, ax3;
#define MKAXR(DST, OR, SC) { \
    const float* xr_ = Wih + (size_t)(OR) * NI + lk * 4; \
    DST[0] = (_Float16)(xr_[0] * (SC)); DST[1] = (_Float16)(xr_[1] * (SC)); \
    DST[2] = (_Float16)(xr_[2] * (SC)); DST[3] = (_Float16)(xr_[3] * (SC)); \
    DST[4] = (_Float16)(bv[(OR)] * (SC)); \
    DST[5] = (_Float16)0.f; DST[6] = (_Float16)0.f; DST[7] = (_Float16)0.f; }
    MKAXR(ax0, or0, s0) MKAXR(ax1, or1, s1) MKAXR(ax2, or2, s2) MKAXR(ax3, or3, s3)
#undef MKAXR

    const int d0 = mt0 * 4 + lk, d1 = mt1 * 4 + lk, d2 = mt2 * 4 + lk, d3 = mt3 * 4 + lk;

    const int hro0 = 0 * 1024 + lk * 256 + lr * 16;
    const int hro1 = 1 * 1024 + lk * 256 + lr * 16;
    const int hro2 = 2 * 1024 + lk * 256 + lr * 16;
    const int hro3 = 3 * 1024 + lk * 256 + lr * 16;
#define CWB(D) ((((D) >> 5) * 1024) + ((((D) & 15) >> 2) * 256) + lr * 16 + (((((D) & 31) >> 4) * 4 + ((D) & 3)) * 2))
    const int cwb0 = CWB(d0), cwb1 = CWB(d1), cwb2 = CWB(d2), cwb3 = CWB(d3);
    // init h/c from encoder st (thread covers its own 4 cells)
    float cs0, cs1, cs2, cs3;
    {
        _Float16* hini = cell ? hB0 : hF0;
        const size_t bs = ((size_t)(b0 + lr) * 2 + cell) * 2 * NH;
        *(_Float16*)((char*)hini + cwb0) = (_Float16)st[bs + d0];  cs0 = st[bs + NH + d0];
        *(_Float16*)((char*)hini + cwb1) = (_Float16)st[bs + d1];  cs1 = st[bs + NH + d1];
        *(_Float16*)((char*)hini + cwb2) = (_Float16)st[bs + d2];  cs2 = st[bs + NH + d2];
        *(_Float16*)((char*)hini + cwb3) = (_Float16)st[bs + d3];  cs3 = st[bs + NH + d3];
    }
#undef CWB
    // init inp = x[:, -1, :]
    if (t < 128) {
        const int ilr = t >> 3, idw = t & 7;
        const float2 v = *(const float2*)(x + ((size_t)(b0 + ilr) * TB + (TB - 1)) * NI + idw * 2);
        inpH[ilr * 8 + idw] = packf16(v.x, v.y);
    }
    // out-proj bias (lane owns outs 4lk..4lk+3)
    const float bl0 = blin[4 * lk + 0], bl1 = blin[4 * lk + 1];
    const float bl2 = blin[4 * lk + 2], bl3 = blin[4 * lk + 3];
    const unsigned int oneku = (lk == 0) ? 0x00003c00u : 0u;
    const f32x4 CZ = {0.f, 0.f, 0.f, 0.f};
    __syncthreads();

    f32x4 Ch0, Ch1, Ch2, Ch3;   // h-part of gates, computed one phase ahead

#define CHCOMP(HRF, HRB) { \
    const char* hr_ = cell ? (const char*)(HRB) : (const char*)(HRF); \
    f16x8 bh_; \
    bh_ = *(const f16x8*)(hr_ + hro0); \
    Ch0 = MFMA(w0_0, bh_, CZ);  Ch1 = MFMA(w1_0, bh_, CZ); \
    Ch2 = MFMA(w2_0, bh_, CZ);  Ch3 = MFMA(w3_0, bh_, CZ); \
    bh_ = *(const f16x8*)(hr_ + hro1); \
    Ch0 = MFMA(w0_1, bh_, Ch0); Ch1 = MFMA(w1_1, bh_, Ch1); \
    Ch2 = MFMA(w2_1, bh_, Ch2); Ch3 = MFMA(w3_1, bh_, Ch3); \
    bh_ = *(const f16x8*)(hr_ + hro2); \
    Ch0 = MFMA(w0_2, bh_, Ch0); Ch1 = MFMA(w1_2, bh_, Ch1); \
    Ch2 = MFMA(w2_2, bh_, Ch2); Ch3 = MFMA(w3_2, bh_, Ch3); \
    bh_ = *(const f16x8*)(hr_ + hro3); \
    Ch0 = MFMA(w0_3, bh_, Ch0); Ch1 = MFMA(w1_3, bh_, Ch1); \
    Ch2 = MFMA(w2_3, bh_, Ch2); Ch3 = MFMA(w3_3, bh_, Ch3); }

#define P3BODY(HRF, HRB, S) { \
    f32x4 P = CZ; \
    _Pragma("unroll") \
    for (int f = 0; f < 8; ++f) { \
        f16x8 af_ = *(const f16x8*)((const char*)wlin_s + opaque((f * 64 + l) * 16)); \
        const char* hb_ = (f < 4) ? (const char*)(HRF) + f * 1024 \
                                  : (const char*)(HRB) + (f - 4) * 1024; \
        f16x8 bf_ = *(const f16x8*)(hb_ + lk * 256 + lr * 16); \
        P = MFMA(af_, bf_, P); \
    } \
    float o0 = P[0] + bl0, o1 = P[1] + bl1, o2 = P[2] + bl2, o3 = P[3] + bl3; \
    float* ob_ = obuf + (S) * 256 + (4 * lk) * 16 + lr; \
    ob_[0] = o0; ob_[16] = o1; ob_[32] = o2; ob_[48] = o3; \
    inpH[lr * 8 + lk * 2]     = packf16(o0, o1); \
    inpH[lr * 8 + lk * 2 + 1] = packf16(o2, o3); }

#define STEPA(HWF, HWB) { \
    char* hw_ = cell ? (char*)(HWB) : (char*)(HWF); \
    f16x8 bx; \
    { uint2 xq_ = *(const uint2*)((const char*)inpH + lr * 32 + lk * 8); \
      ((unsigned int*)&bx)[0] = xq_.x; ((unsigned int*)&bx)[1] = xq_.y; \
      ((unsigned int*)&bx)[2] = oneku; ((unsigned int*)&bx)[3] = 0u; } \
    f32x4 C0 = MFMA(ax0, bx, Ch0); f32x4 C1 = MFMA(ax1, bx, Ch1); \
    f32x4 C2 = MFMA(ax2, bx, Ch2); f32x4 C3 = MFMA(ax3, bx, Ch3); \
    CELLBODY(C0, cs0, hw_, cwb0) \
    CELLBODY(C1, cs1, hw_, cwb1) \
    CELLBODY(C2, cs2, hw_, cwb2) \
    CELLBODY(C3, cs3, hw_, cwb3) \
    __syncthreads(); }

#define STEPB(HRF, HRB, S) { \
    CHCOMP(HRF, HRB) \
    if (wv == 0) { P3BODY(HRF, HRB, S) } \
    __syncthreads(); }

    // prologue: h-part of gates for step 0 from h_0 (inp_0 already staged)
    CHCOMP(hF0, hB0)

    for (int s2 = 0; s2 < PRED / 2; ++s2) {
        STEPA(hF1, hB1)            // h_1 -> buf1 (gates = Ch + ax*bx(inp_0))
        STEPB(hF1, hB1, s2 * 2)    // Ch' from buf1 || wave0: out_0, inp_1
        STEPA(hF0, hB0)            // h_2 -> buf0
        STEPB(hF0, hB0, s2 * 2 + 1)
    }
#undef STEPB
#undef STEPA
#undef P3BODY
#undef CHCOMP

    // flush obuf -> out (coalesced: consecutive i -> consecutive global)
    for (int i = t; i < PRED * 256; i += 1024) {
        const int lr2 = i / (PRED * NI);
        const int rem = i - lr2 * (PRED * NI);
        const int s   = rem >> 4;
        const int j   = rem & 15;
        out[(size_t)(b0 + lr2) * PRED * NI + rem] = obuf[s * 256 + j * 16 + lr2];
    }
}

extern "C" void kernel_launch(void* const* d_in, const int* in_sizes, int n_in,
                              void* d_out, int out_size, void* d_ws, size_t ws_size,
                              hipStream_t stream)
{
    const float* x      = (const float*)d_in[0];
    const float* eWih_f = (const float*)d_in[1];
    const float* eWhh_f = (const float*)d_in[2];
    const float* eb_f   = (const float*)d_in[3];
    const float* eWih_b = (const float*)d_in[4];
    const float* eWhh_b = (const float*)d_in[5];
    const float* eb_b   = (const float*)d_in[6];
    const float* dWih_f = (const float*)d_in[7];
    const float* dWhh_f = (const float*)d_in[8];
    const float* db_f   = (const float*)d_in[9];
    const float* dWih_b = (const float*)d_in[10];
    const float* dWhh_b = (const float*)d_in[11];
    const float* db_b   = (const float*)d_in[12];
    const float* Wlin   = (const float*)d_in[13];
    const float* blin   = (const float*)d_in[14];

    float* st = (float*)d_ws;  // 256*2*2*128 f32 encoder final states

    enc_kernel<<<32, 1024, 0, stream>>>(x, eWih_f, eWhh_f, eb_f, eWih_b, eWhh_b, eb_b, st);
    dec_kernel<<<16, 1024, 0, stream>>>(x, dWih_f, dWhh_f, db_f, dWih_b, dWhh_b, db_b,
                                        Wlin, blin, st, (float*)d_out);
}

// Round 21
// 717.036 us; speedup vs baseline: 1.1124x; 1.1124x over previous
//
#include <hip/hip_runtime.h>
#include <math.h>

#define TB    720
#define NI    16
#define NH    128
#define NG    512
#define PRED  96
#define CHUNK 90          // 720 = 8 * 90

typedef _Float16 h2    __attribute__((ext_vector_type(2)));
typedef _Float16 f16x4 __attribute__((ext_vector_type(4)));
typedef _Float16 f16x8 __attribute__((ext_vector_type(8)));
typedef float    f32x4 __attribute__((ext_vector_type(4)));

#define LOG2E  1.4426950408889634f
#define LOG2E2 2.8853900817779268f

__device__ __forceinline__ float rcpf_(float v) {
#if __has_builtin(__builtin_amdgcn_rcpf)
    return __builtin_amdgcn_rcpf(v);
#else
    return 1.0f / v;
#endif
}
__device__ __forceinline__ float ex2(float v) {
#if __has_builtin(__builtin_amdgcn_exp2f)
    return __builtin_amdgcn_exp2f(v);
#else
    return exp2f(v);
#endif
}
__device__ __forceinline__ float sigf(float v)   { return rcpf_(1.0f + __expf(-v)); }
__device__ __forceinline__ float tanhf_(float v) { return 1.0f - 2.0f * rcpf_(1.0f + __expf(2.0f * v)); }

__device__ __forceinline__ unsigned int packf16(float a, float b) {
    h2 p; p.x = (_Float16)a; p.y = (_Float16)b;
    return __builtin_bit_cast(unsigned int, p);
}
__device__ __forceinline__ float2 unpackf16(unsigned int u) {
    h2 p = __builtin_bit_cast(h2, u);
    return make_float2((float)p.x, (float)p.y);
}
__device__ __forceinline__ float fdot2f(unsigned int a, unsigned int b, float c) {
#if __has_builtin(__builtin_amdgcn_fdot2)
    return __builtin_amdgcn_fdot2(__builtin_bit_cast(h2, a), __builtin_bit_cast(h2, b), c, false);
#else
    h2 x = __builtin_bit_cast(h2, a), y = __builtin_bit_cast(h2, b);
    return c + (float)x.x * (float)y.x + (float)x.y * (float)y.y;
#endif
}

// A/B frag split-half k layout (verified R9-R18); scaled variant for exp2 gates
__device__ __forceinline__ f16x8 mk8s(const float* p, float s) {
    f16x8 v;
    v[0] = (_Float16)(p[0]  * s); v[1] = (_Float16)(p[1]  * s);
    v[2] = (_Float16)(p[2]  * s); v[3] = (_Float16)(p[3]  * s);
    v[4] = (_Float16)(p[16] * s); v[5] = (_Float16)(p[17] * s);
    v[6] = (_Float16)(p[18] * s); v[7] = (_Float16)(p[19] * s);
    return v;
}
__device__ __forceinline__ f32x4 MFMA(f16x8 a, f16x8 b, f32x4 c) {
    return __builtin_amdgcn_mfma_f32_16x16x32_f16(a, b, c, 0, 0, 0);
}

// DPP wave64 reduce (VALU pipe, not LDS like __shfl). Ctrl/rmask are
// template params: __builtin_amdgcn_update_dpp requires literal constants.
template <int CTRL, int RMASK>
__device__ __forceinline__ float dppadd(float v) {
    int s = __builtin_bit_cast(int, v);
    int d = __builtin_amdgcn_update_dpp(0, s, CTRL, RMASK, 0xf, true);
    return v + __builtin_bit_cast(float, d);
}

// ---------------- encoder (R18 best-known: ~540 us) ----------------
// grid 32 = (batch/16) x dir; 16 waves, wave owns 2 m-tiles. ALL weights
// register-resident: 8 wh frags (32 VGPR) + 2 ax frags (8 VGPR, bias in
// elem4, ones-column via bx[4]). 5 LDS reads/thread/step.
__global__ __launch_bounds__(1024, 4)
void enc_kernel(const float* __restrict__ x,
                const float* __restrict__ Wih_f, const float* __restrict__ Whh_f, const float* __restrict__ b_f,
                const float* __restrict__ Wih_b, const float* __restrict__ Whh_b, const float* __restrict__ b_b,
                float* __restrict__ st)   // st[b][dir][{h,c}][NH]
{
    __shared__ _Float16 hbuf0[16 * NH];        // 4KB frag-major
    __shared__ _Float16 hbuf1[16 * NH];
    __shared__ unsigned int xsh[CHUNK * 128];  // 46KB

    const int blk = blockIdx.x;
    const int dir = blk & 1;
    const int b0  = (blk >> 1) << 4;
    const int t   = threadIdx.x;
    const int wv  = t >> 6;      // 0..15
    const int l   = t & 63;
    const int lr  = l & 15;
    const int lk  = l >> 4;

    const float* Wih = dir ? Wih_b : Wih_f;
    const float* Whh = dir ? Whh_b : Whh_f;
    const float* bv  = dir ? b_b   : b_f;

    // ---- resident Whh frags: 2 m-tiles x 4 frags = 32 VGPR ----
    const int mt0 = 2 * wv, mt1 = 2 * wv + 1;
    const int R0 = mt0 * 16 + lr, R1 = mt1 * 16 + lr;
    const int or0 = (R0 & 3) * 128 + (R0 >> 2);
    const int or1 = (R1 & 3) * 128 + (R1 >> 2);
    const float s0 = ((or0 >> 7) == 2) ? LOG2E2 : LOG2E;
    const float s1 = ((or1 >> 7) == 2) ? LOG2E2 : LOG2E;
    const float* p0 = Whh + (size_t)or0 * NH + lk * 4;
    const float* p1 = Whh + (size_t)or1 * NH + lk * 4;
    f16x8 w0_0 = mk8s(p0, s0), w0_1 = mk8s(p0 + 32, s0), w0_2 = mk8s(p0 + 64, s0), w0_3 = mk8s(p0 + 96, s0);
    f16x8 w1_0 = mk8s(p1, s1), w1_1 = mk8s(p1 + 32, s1), w1_2 = mk8s(p1 + 64, s1), w1_3 = mk8s(p1 + 96, s1);

    // ---- resident x-weight frags, bias at elem4 (k==16; pairs with bx[4]=1 @ lk==0)
    f16x8 ax0, ax1;
#define MKAXR(DST, OR, SC) { \
    const float* xr_ = Wih + (size_t)(OR) * NI + lk * 4; \
    DST[0] = (_Float16)(xr_[0] * (SC)); DST[1] = (_Float16)(xr_[1] * (SC)); \
    DST[2] = (_Float16)(xr_[2] * (SC)); DST[3] = (_Float16)(xr_[3] * (SC)); \
    DST[4] = (_Float16)(bv[(OR)] * (SC)); \
    DST[5] = (_Float16)0.f; DST[6] = (_Float16)0.f; DST[7] = (_Float16)0.f; }
    MKAXR(ax0, or0, s0) MKAXR(ax1, or1, s1)
#undef MKAXR

    const int d0 = mt0 * 4 + lk, d1 = mt1 * 4 + lk;

    ((unsigned int*)hbuf0)[t] = 0u;   // 1024 dwords, one per thread
    float cs0 = 0.f, cs1 = 0.f;

    const int hro0 = 0 * 1024 + lk * 256 + lr * 16;
    const int hro1 = 1 * 1024 + lk * 256 + lr * 16;
    const int hro2 = 2 * 1024 + lk * 256 + lr * 16;
    const int hro3 = 3 * 1024 + lk * 256 + lr * 16;
#define CWB(D) ((((D) >> 5) * 1024) + ((((D) & 15) >> 2) * 256) + lr * 16 + (((((D) & 31) >> 4) * 4 + ((D) & 3)) * 2))
    const int cwb0 = CWB(d0), cwb1 = CWB(d1);
#undef CWB
    const int xoff = lk * 128 + lr * 8;
    const unsigned int oneku = (lk == 0) ? 0x00003c00u : 0u;  // f16 1.0 -> bx elem4
    const f32x4 CZ = {0.f, 0.f, 0.f, 0.f};
    __syncthreads();

#define CELL(J, HW) { \
    float ei_ = ex2(-C##J[0]), ef_ = ex2(-C##J[1]); \
    float eg_ = ex2(C##J[2]),  eo_ = ex2(-C##J[3]); \
    float di_ = 1.f + ei_, df_ = 1.f + ef_, dg_ = 1.f + eg_, dq_ = 1.f + eo_; \
    float r1_ = rcpf_(di_ * df_), r2_ = rcpf_(dq_ * dg_); \
    float si_ = r1_ * df_, sf_ = r1_ * di_, so_ = r2_ * dg_; \
    float tg_ = __builtin_fmaf(-2.f * r2_, dq_, 1.f); \
    cs##J = sf_ * cs##J + si_ * tg_; \
    float ec_ = ex2(cs##J * LOG2E2); \
    float th_ = __builtin_fmaf(-2.f, rcpf_(1.f + ec_), 1.f); \
    float hv_ = so_ * th_; \
    *(_Float16*)((char*)(HW) + cwb##J) = (_Float16)hv_; }

#define STEP(HR, HW, SI) { \
    const char* hrb_ = (const char*)(HR); \
    f16x8 bx; \
    { uint2 xq_ = *(const uint2*)((const char*)xsh + (SI) * 512 + xoff); \
      ((unsigned int*)&bx)[0] = xq_.x; ((unsigned int*)&bx)[1] = xq_.y; \
      ((unsigned int*)&bx)[2] = oneku; ((unsigned int*)&bx)[3] = 0u; } \
    f32x4 C0 = MFMA(ax0, bx, CZ); \
    f32x4 C1 = MFMA(ax1, bx, CZ); \
    f16x8 bh_; \
    bh_ = *(const f16x8*)(hrb_ + hro0); \
    C0 = MFMA(w0_0, bh_, C0); C1 = MFMA(w1_0, bh_, C1); \
    bh_ = *(const f16x8*)(hrb_ + hro1); \
    C0 = MFMA(w0_1, bh_, C0); C1 = MFMA(w1_1, bh_, C1); \
    bh_ = *(const f16x8*)(hrb_ + hro2); \
    C0 = MFMA(w0_2, bh_, C0); C1 = MFMA(w1_2, bh_, C1); \
    bh_ = *(const f16x8*)(hrb_ + hro3); \
    C0 = MFMA(w0_3, bh_, C0); C1 = MFMA(w1_3, bh_, C1); \
    CELL(0, HW) CELL(1, HW) \
    __syncthreads(); }

    for (int c = 0; c < 8; ++c) {
        {
            const int c0 = c * CHUNK;
            for (int i = t; i < 16 * CHUNK * 8; i += 1024) {
                const int br  = i / (CHUNK * 8);
                const int rem = i - br * (CHUNK * 8);
                const int ti  = rem >> 3;
                const int dw  = rem & 7;
                const int s_  = c0 + ti;
                const int tt  = dir ? (TB - 1 - s_) : s_;
                float2 v = *(const float2*)(x + ((size_t)(b0 + br) * TB + tt) * NI + dw * 2);
                xsh[ti * 128 + (dw >> 1) * 32 + br * 2 + (dw & 1)] = packf16(v.x, v.y);
            }
        }
        __syncthreads();
        for (int si2 = 0; si2 < CHUNK / 2; ++si2) {
            STEP(hbuf0, hbuf1, si2 * 2)
            STEP(hbuf1, hbuf0, si2 * 2 + 1)
        }
    }
#undef STEP
#undef CELL

    // final states: h in hbuf0 (720 even), c in regs
    {
        const size_t base = ((size_t)(b0 + lr) * 2 + dir) * 2 * NH;
#define CWB(D) ((((D) >> 5) * 1024) + ((((D) & 15) >> 2) * 256) + lr * 16 + (((((D) & 31) >> 4) * 4 + ((D) & 3)) * 2))
        st[base + d0]      = (float)*(const _Float16*)((const char*)hbuf0 + CWB(d0));
        st[base + NH + d0] = cs0;
        st[base + d1]      = (float)*(const _Float16*)((const char*)hbuf0 + CWB(d1));
        st[base + NH + d1] = cs1;
#undef CWB
    }
}

// named-var repetition macros (arrays get scratch-demoted: R4/R6 evidence)
#define R8(F)  F(0)F(1)F(2)F(3)F(4)F(5)F(6)F(7)
#define R36_(F) F(8)F(9)F(10)F(11)F(12)F(13)F(14)F(15)F(16)F(17)F(18)F(19)F(20)F(21)F(22)F(23)F(24)F(25)F(26)F(27)F(28)F(29)F(30)F(31)F(32)F(33)F(34)F(35)
#define R36(F) R8(F) R36_(F)
#define R64(F) R36(F) F(36)F(37)F(38)F(39)F(40)F(41)F(42)F(43)F(44)F(45)F(46)F(47)F(48)F(49)F(50)F(51)F(52)F(53)F(54)F(55)F(56)F(57)F(58)F(59)F(60)F(61)F(62)F(63)

#define QD(Q,i0,i1,i2,i3) { a0 = fdot2f((Q).x, w##i0, a0); a1 = fdot2f((Q).y, w##i1, a1); \
                            a2 = fdot2f((Q).z, w##i2, a2); a3 = fdot2f((Q).w, w##i3, a3); }
#define QDU(Q,i0,i1,i2,i3) { a0 = fdot2f((Q).x, u##i0, a0); a1 = fdot2f((Q).y, u##i1, a1); \
                             a2 = fdot2f((Q).z, u##i2, a2); a3 = fdot2f((Q).w, u##i3, a3); }

// ---------------- decoder (R18 best-known: ~176 us; 256 blocks, DPP reduce) ----------------
__global__ __launch_bounds__(1024, 1)
void dec_kernel(const float* __restrict__ x,
                const float* __restrict__ Wih_f, const float* __restrict__ Whh_f, const float* __restrict__ b_f,
                const float* __restrict__ Wih_b, const float* __restrict__ Whh_b, const float* __restrict__ b_b,
                const float* __restrict__ Wlin, const float* __restrict__ blin,
                const float* __restrict__ st, float* __restrict__ out)
{
    __shared__ unsigned int hFh[NH / 2], hBh[NH / 2];
    __shared__ unsigned int inpH[NI / 2];
    __shared__ float g[1024];
    __shared__ float obuf[PRED * 16];    // 6KB output buffer, flushed once at end

    const int b    = blockIdx.x;
    const int t    = threadIdx.x;
    const int cell = t >> 9;
    const int r    = t & 511;
    const int w    = t >> 6;     // wave id = output index (16 waves, 16 outputs)
    const int ln   = t & 63;

    const float* Wih = cell ? Wih_b : Wih_f;
    const float* Whh = cell ? Whh_b : Whh_f;
    const float* bv  = cell ? b_b   : b_f;

#define DW(K) unsigned int w##K;
    R64(DW)
#undef DW
#define DU(K) unsigned int u##K;
    R8(DU)
#undef DU
    {
        const float* xr = Wih + r * NI;
        const float* hr = Whh + r * NH;
#define LU(K) u##K = packf16(xr[2*(K)], xr[2*(K)+1]);
        R8(LU)
#undef LU
#define LH(K) w##K = packf16(hr[2*(K)], hr[2*(K)+1]);
        R64(LH)
#undef LH
    }
    const float bias = bv[r];

    // out-projection statics: wave w, lane ln covers concat cols 4ln..4ln+3
    const float wl0 = Wlin[w * 256 + ln * 4 + 0];
    const float wl1 = Wlin[w * 256 + ln * 4 + 1];
    const float wl2 = Wlin[w * 256 + ln * 4 + 2];
    const float wl3 = Wlin[w * 256 + ln * 4 + 3];
    const float blw = blin[w];

    float cc = 0.0f;
    if (t < 64) {
        const float* sh = st + ((b * 2 + 0) * 2 + 0) * NH;
        hFh[t] = packf16(sh[2 * t], sh[2 * t + 1]);
    } else if (t < 128) {
        const float* sh = st + ((b * 2 + 1) * 2 + 0) * NH;
        hBh[t - 64] = packf16(sh[2 * (t - 64)], sh[2 * (t - 64) + 1]);
    }
    if (t < NH) cc = st[((b * 2 + 0) * 2 + 1) * NH + t];
    else if (t >= 512 && t < 512 + NH) cc = st[((b * 2 + 1) * 2 + 1) * NH + (t - 512)];
    if (t < 8) {
        float2 v = ((const float2*)(x + (size_t)b * TB * NI + (TB - 1) * NI))[t];
        inpH[t] = packf16(v.x, v.y);
    }
    __syncthreads();

    for (int s = 0; s < PRED; ++s) {
        // ---- P1: gates ----
        float a0 = bias, a1 = 0.f, a2 = 0.f, a3 = 0.f;
        uint4 q;
        {
            const uint4* xv = (const uint4*)inpH;
            q = xv[0]; QDU(q, 0, 1, 2, 3)
            q = xv[1]; QDU(q, 4, 5, 6, 7)
        }
        const uint4* hv = cell ? (const uint4*)hBh : (const uint4*)hFh;
        q = hv[0];  QD(q, 0, 1, 2, 3)
        q = hv[1];  QD(q, 4, 5, 6, 7)
        q = hv[2];  QD(q, 8, 9, 10, 11)
        q = hv[3];  QD(q, 12, 13, 14, 15)
        q = hv[4];  QD(q, 16, 17, 18, 19)
        q = hv[5];  QD(q, 20, 21, 22, 23)
        q = hv[6];  QD(q, 24, 25, 26, 27)
        q = hv[7];  QD(q, 28, 29, 30, 31)
        q = hv[8];  QD(q, 32, 33, 34, 35)
        q = hv[9];  QD(q, 36, 37, 38, 39)
        q = hv[10]; QD(q, 40, 41, 42, 43)
        q = hv[11]; QD(q, 44, 45, 46, 47)
        q = hv[12]; QD(q, 48, 49, 50, 51)
        q = hv[13]; QD(q, 52, 53, 54, 55)
        q = hv[14]; QD(q, 56, 57, 58, 59)
        q = hv[15]; QD(q, 60, 61, 62, 63)
        g[t] = (a0 + a1) + (a2 + a3);
        __syncthreads();

        // ---- P2: cell update ----
        if ((t < NH) || (t >= 512 && t < 512 + NH)) {
            float gi = g[t], gf = g[t + NH], gg = g[t + 2 * NH], go = g[t + 3 * NH];
            cc = sigf(gf) * cc + sigf(gi) * tanhf_(gg);
            float h = sigf(go) * tanhf_(cc);
            if (t < NH) ((_Float16*)hFh)[t] = (_Float16)h;
            else        ((_Float16*)hBh)[t - 512] = (_Float16)h;
        }
        __syncthreads();

        // ---- P3: out[w] = concat(hF,hB).Wlin[w] + blin[w]; DPP reduce -> lane 63
        {
            const unsigned int* hsrc = (ln < 32) ? (hFh + 2 * ln) : (hBh + 2 * (ln - 32));
            uint2 hw = *(const uint2*)hsrc;
            float2 va = unpackf16(hw.x), vb = unpackf16(hw.y);
            float p = va.x * wl0 + va.y * wl1 + vb.x * wl2 + vb.y * wl3;
            p = dppadd<0x111, 0xf>(p);   // row_shr:1
            p = dppadd<0x112, 0xf>(p);   // row_shr:2
            p = dppadd<0x114, 0xf>(p);   // row_shr:4
            p = dppadd<0x118, 0xf>(p);   // row_shr:8  -> lane 15/31/47/63 = row sums
            p = dppadd<0x142, 0xa>(p);   // row_bcast15 -> rows 1,3
            p = dppadd<0x143, 0xc>(p);   // row_bcast31 -> rows 2,3; total @ lane 63
            if (ln == 63) {
                float o = p + blw;
                obuf[s * NI + w] = o;
                ((_Float16*)inpH)[w] = (_Float16)o;
            }
        }
        __syncthreads();
    }

    // flush outputs once (coalesced float4)
    {
        float4* dst = (float4*)(out + (size_t)b * PRED * NI);
        const float4* src = (const float4*)obuf;
        for (int i = t; i < PRED * NI / 4; i += 1024) dst[i] = src[i];
    }
}

extern "C" void kernel_launch(void* const* d_in, const int* in_sizes, int n_in,
                              void* d_out, int out_size, void* d_ws, size_t ws_size,
                              hipStream_t stream)
{
    const float* x      = (const float*)d_in[0];
    const float* eWih_f = (const float*)d_in[1];
    const float* eWhh_f = (const float*)d_in[2];
    const float* eb_f   = (const float*)d_in[3];
    const float* eWih_b = (const float*)d_in[4];
    const float* eWhh_b = (const float*)d_in[5];
    const float* eb_b   = (const float*)d_in[6];
    const float* dWih_f = (const float*)d_in[7];
    const float* dWhh_f = (const float*)d_in[8];
    const float* db_f   = (const float*)d_in[9];
    const float* dWih_b = (const float*)d_in[10];
    const float* dWhh_b = (const float*)d_in[11];
    const float* db_b   = (const float*)d_in[12];
    const float* Wlin   = (const float*)d_in[13];
    const float* blin   = (const float*)d_in[14];

    float* st = (float*)d_ws;  // 256*2*2*128 f32 encoder final states

    enc_kernel<<<32, 1024, 0, stream>>>(x, eWih_f, eWhh_f, eb_f, eWih_b, eWhh_b, eb_b, st);
    dec_kernel<<<256, 1024, 0, stream>>>(x, dWih_f, dWhh_f, db_f, dWih_b, dWhh_b, db_b,
                                         Wlin, blin, st, (float*)d_out);
}

// Round 22
// 715.096 us; speedup vs baseline: 1.1154x; 1.0027x over previous
//
#include <hip/hip_runtime.h>
#include <math.h>

#define TB    720
#define NI    16
#define NH    128
#define NG    512
#define PRED  96
#define CHUNK 90          // 720 = 8 * 90

typedef _Float16 h2    __attribute__((ext_vector_type(2)));
typedef _Float16 f16x4 __attribute__((ext_vector_type(4)));
typedef _Float16 f16x8 __attribute__((ext_vector_type(8)));
typedef float    f32x4 __attribute__((ext_vector_type(4)));

#define LOG2E  1.4426950408889634f
#define LOG2E2 2.8853900817779268f

__device__ __forceinline__ float rcpf_(float v) {
#if __has_builtin(__builtin_amdgcn_rcpf)
    return __builtin_amdgcn_rcpf(v);
#else
    return 1.0f / v;
#endif
}
__device__ __forceinline__ float ex2(float v) {
#if __has_builtin(__builtin_amdgcn_exp2f)
    return __builtin_amdgcn_exp2f(v);
#else
    return exp2f(v);
#endif
}
__device__ __forceinline__ float sigf(float v)   { return rcpf_(1.0f + __expf(-v)); }
__device__ __forceinline__ float tanhf_(float v) { return 1.0f - 2.0f * rcpf_(1.0f + __expf(2.0f * v)); }

__device__ __forceinline__ unsigned int packf16(float a, float b) {
    h2 p; p.x = (_Float16)a; p.y = (_Float16)b;
    return __builtin_bit_cast(unsigned int, p);
}
__device__ __forceinline__ float2 unpackf16(unsigned int u) {
    h2 p = __builtin_bit_cast(h2, u);
    return make_float2((float)p.x, (float)p.y);
}
__device__ __forceinline__ float fdot2f(unsigned int a, unsigned int b, float c) {
#if __has_builtin(__builtin_amdgcn_fdot2)
    return __builtin_amdgcn_fdot2(__builtin_bit_cast(h2, a), __builtin_bit_cast(h2, b), c, false);
#else
    h2 x = __builtin_bit_cast(h2, a), y = __builtin_bit_cast(h2, b);
    return c + (float)x.x * (float)y.x + (float)x.y * (float)y.y;
#endif
}

// A/B frag split-half k layout (verified R9-R21); scaled variant for exp2 gates
__device__ __forceinline__ f16x8 mk8s(const float* p, float s) {
    f16x8 v;
    v[0] = (_Float16)(p[0]  * s); v[1] = (_Float16)(p[1]  * s);
    v[2] = (_Float16)(p[2]  * s); v[3] = (_Float16)(p[3]  * s);
    v[4] = (_Float16)(p[16] * s); v[5] = (_Float16)(p[17] * s);
    v[6] = (_Float16)(p[18] * s); v[7] = (_Float16)(p[19] * s);
    return v;
}
__device__ __forceinline__ f32x4 MFMA(f16x8 a, f16x8 b, f32x4 c) {
    return __builtin_amdgcn_mfma_f32_16x16x32_f16(a, b, c, 0, 0, 0);
}

// DPP wave64 reduce (VALU pipe, not LDS like __shfl). Ctrl/rmask are
// template params: __builtin_amdgcn_update_dpp requires literal constants.
template <int CTRL, int RMASK>
__device__ __forceinline__ float dppadd(float v) {
    int s = __builtin_bit_cast(int, v);
    int d = __builtin_amdgcn_update_dpp(0, s, CTRL, RMASK, 0xf, true);
    return v + __builtin_bit_cast(float, d);
}

// ---------------- encoder (R18 + x-part hoisted into barrier shadow) ----------------
// grid 32 = (batch/16) x dir; 16 waves, wave owns 2 m-tiles; all weights in
// VGPR. NEW: Cx(s+1) = MFMA(ax, bx(s+1)) computed between CELL and the
// barrier -- x-part doesn't depend on h, so it hides in the barrier wait
// instead of serializing after it. Chunk-boundary Cx recomputed in prologue.
__global__ __launch_bounds__(1024, 4)
void enc_kernel(const float* __restrict__ x,
                const float* __restrict__ Wih_f, const float* __restrict__ Whh_f, const float* __restrict__ b_f,
                const float* __restrict__ Wih_b, const float* __restrict__ Whh_b, const float* __restrict__ b_b,
                float* __restrict__ st)   // st[b][dir][{h,c}][NH]
{
    __shared__ _Float16 hbuf0[16 * NH];        // 4KB frag-major
    __shared__ _Float16 hbuf1[16 * NH];
    __shared__ unsigned int xsh[CHUNK * 128];  // 46KB

    const int blk = blockIdx.x;
    const int dir = blk & 1;
    const int b0  = (blk >> 1) << 4;
    const int t   = threadIdx.x;
    const int wv  = t >> 6;      // 0..15
    const int l   = t & 63;
    const int lr  = l & 15;
    const int lk  = l >> 4;

    const float* Wih = dir ? Wih_b : Wih_f;
    const float* Whh = dir ? Whh_b : Whh_f;
    const float* bv  = dir ? b_b   : b_f;

    // ---- resident Whh frags: 2 m-tiles x 4 frags = 32 VGPR ----
    const int mt0 = 2 * wv, mt1 = 2 * wv + 1;
    const int R0 = mt0 * 16 + lr, R1 = mt1 * 16 + lr;
    const int or0 = (R0 & 3) * 128 + (R0 >> 2);
    const int or1 = (R1 & 3) * 128 + (R1 >> 2);
    const float s0 = ((or0 >> 7) == 2) ? LOG2E2 : LOG2E;
    const float s1 = ((or1 >> 7) == 2) ? LOG2E2 : LOG2E;
    const float* p0 = Whh + (size_t)or0 * NH + lk * 4;
    const float* p1 = Whh + (size_t)or1 * NH + lk * 4;
    f16x8 w0_0 = mk8s(p0, s0), w0_1 = mk8s(p0 + 32, s0), w0_2 = mk8s(p0 + 64, s0), w0_3 = mk8s(p0 + 96, s0);
    f16x8 w1_0 = mk8s(p1, s1), w1_1 = mk8s(p1 + 32, s1), w1_2 = mk8s(p1 + 64, s1), w1_3 = mk8s(p1 + 96, s1);

    // ---- resident x-weight frags, bias at elem4 (k==16; pairs with bx[4]=1 @ lk==0)
    f16x8 ax0, ax1;
#define MKAXR(DST, OR, SC) { \
    const float* xr_ = Wih + (size_t)(OR) * NI + lk * 4; \
    DST[0] = (_Float16)(xr_[0] * (SC)); DST[1] = (_Float16)(xr_[1] * (SC)); \
    DST[2] = (_Float16)(xr_[2] * (SC)); DST[3] = (_Float16)(xr_[3] * (SC)); \
    DST[4] = (_Float16)(bv[(OR)] * (SC)); \
    DST[5] = (_Float16)0.f; DST[6] = (_Float16)0.f; DST[7] = (_Float16)0.f; }
    MKAXR(ax0, or0, s0) MKAXR(ax1, or1, s1)
#undef MKAXR

    const int d0 = mt0 * 4 + lk, d1 = mt1 * 4 + lk;

    ((unsigned int*)hbuf0)[t] = 0u;   // 1024 dwords, one per thread
    float cs0 = 0.f, cs1 = 0.f;

    const int hro0 = 0 * 1024 + lk * 256 + lr * 16;
    const int hro1 = 1 * 1024 + lk * 256 + lr * 16;
    const int hro2 = 2 * 1024 + lk * 256 + lr * 16;
    const int hro3 = 3 * 1024 + lk * 256 + lr * 16;
#define CWB(D) ((((D) >> 5) * 1024) + ((((D) & 15) >> 2) * 256) + lr * 16 + (((((D) & 31) >> 4) * 4 + ((D) & 3)) * 2))
    const int cwb0 = CWB(d0), cwb1 = CWB(d1);
#undef CWB
    const int xoff = lk * 128 + lr * 8;
    const unsigned int oneku = (lk == 0) ? 0x00003c00u : 0u;  // f16 1.0 -> bx elem4
    const f32x4 CZ = {0.f, 0.f, 0.f, 0.f};
    f32x4 Cx0, Cx1;            // x-part of gates, computed one step ahead
    __syncthreads();

#define MKCX(SI) { \
    f16x8 bx_; \
    uint2 xq_ = *(const uint2*)((const char*)xsh + (SI) * 512 + xoff); \
    ((unsigned int*)&bx_)[0] = xq_.x; ((unsigned int*)&bx_)[1] = xq_.y; \
    ((unsigned int*)&bx_)[2] = oneku; ((unsigned int*)&bx_)[3] = 0u; \
    Cx0 = MFMA(ax0, bx_, CZ); Cx1 = MFMA(ax1, bx_, CZ); }

#define CELL(J, HW) { \
    float ei_ = ex2(-C##J[0]), ef_ = ex2(-C##J[1]); \
    float eg_ = ex2(C##J[2]),  eo_ = ex2(-C##J[3]); \
    float di_ = 1.f + ei_, df_ = 1.f + ef_, dg_ = 1.f + eg_, dq_ = 1.f + eo_; \
    float r1_ = rcpf_(di_ * df_), r2_ = rcpf_(dq_ * dg_); \
    float si_ = r1_ * df_, sf_ = r1_ * di_, so_ = r2_ * dg_; \
    float tg_ = __builtin_fmaf(-2.f * r2_, dq_, 1.f); \
    cs##J = sf_ * cs##J + si_ * tg_; \
    float ec_ = ex2(cs##J * LOG2E2); \
    float th_ = __builtin_fmaf(-2.f, rcpf_(1.f + ec_), 1.f); \
    float hv_ = so_ * th_; \
    *(_Float16*)((char*)(HW) + cwb##J) = (_Float16)hv_; }

// h-MFMAs accumulate onto prefetched Cx; CELL; then speculatively build Cx
// for step SI+1 (stale at chunk boundary -> prologue recomputes) in the
// barrier shadow.
#define STEP(HR, HW, SI) { \
    const char* hrb_ = (const char*)(HR); \
    f32x4 C0 = Cx0, C1 = Cx1; \
    f16x8 bh_; \
    bh_ = *(const f16x8*)(hrb_ + hro0); \
    C0 = MFMA(w0_0, bh_, C0); C1 = MFMA(w1_0, bh_, C1); \
    bh_ = *(const f16x8*)(hrb_ + hro1); \
    C0 = MFMA(w0_1, bh_, C0); C1 = MFMA(w1_1, bh_, C1); \
    bh_ = *(const f16x8*)(hrb_ + hro2); \
    C0 = MFMA(w0_2, bh_, C0); C1 = MFMA(w1_2, bh_, C1); \
    bh_ = *(const f16x8*)(hrb_ + hro3); \
    C0 = MFMA(w0_3, bh_, C0); C1 = MFMA(w1_3, bh_, C1); \
    CELL(0, HW) CELL(1, HW) \
    { const int nsi_ = ((SI) + 1 < CHUNK) ? (SI) + 1 : 0; \
      MKCX(nsi_) } \
    __syncthreads(); }

    for (int c = 0; c < 8; ++c) {
        {
            const int c0 = c * CHUNK;
            for (int i = t; i < 16 * CHUNK * 8; i += 1024) {
                const int br  = i / (CHUNK * 8);
                const int rem = i - br * (CHUNK * 8);
                const int ti  = rem >> 3;
                const int dw  = rem & 7;
                const int s_  = c0 + ti;
                const int tt  = dir ? (TB - 1 - s_) : s_;
                float2 v = *(const float2*)(x + ((size_t)(b0 + br) * TB + tt) * NI + dw * 2);
                xsh[ti * 128 + (dw >> 1) * 32 + br * 2 + (dw & 1)] = packf16(v.x, v.y);
            }
        }
        __syncthreads();
        MKCX(0)                      // prologue: fresh Cx for this chunk's step 0
        for (int si2 = 0; si2 < CHUNK / 2; ++si2) {
            STEP(hbuf0, hbuf1, si2 * 2)
            STEP(hbuf1, hbuf0, si2 * 2 + 1)
        }
    }
#undef STEP
#undef CELL
#undef MKCX

    // final states: h in hbuf0 (720 even), c in regs
    {
        const size_t base = ((size_t)(b0 + lr) * 2 + dir) * 2 * NH;
#define CWB(D) ((((D) >> 5) * 1024) + ((((D) & 15) >> 2) * 256) + lr * 16 + (((((D) & 31) >> 4) * 4 + ((D) & 3)) * 2))
        st[base + d0]      = (float)*(const _Float16*)((const char*)hbuf0 + CWB(d0));
        st[base + NH + d0] = cs0;
        st[base + d1]      = (float)*(const _Float16*)((const char*)hbuf0 + CWB(d1));
        st[base + NH + d1] = cs1;
#undef CWB
    }
}

// named-var repetition macros (arrays get scratch-demoted: R4/R6 evidence)
#define R8(F)  F(0)F(1)F(2)F(3)F(4)F(5)F(6)F(7)
#define R36_(F) F(8)F(9)F(10)F(11)F(12)F(13)F(14)F(15)F(16)F(17)F(18)F(19)F(20)F(21)F(22)F(23)F(24)F(25)F(26)F(27)F(28)F(29)F(30)F(31)F(32)F(33)F(34)F(35)
#define R36(F) R8(F) R36_(F)
#define R64(F) R36(F) F(36)F(37)F(38)F(39)F(40)F(41)F(42)F(43)F(44)F(45)F(46)F(47)F(48)F(49)F(50)F(51)F(52)F(53)F(54)F(55)F(56)F(57)F(58)F(59)F(60)F(61)F(62)F(63)

#define QD(Q,i0,i1,i2,i3) { a0 = fdot2f((Q).x, w##i0, a0); a1 = fdot2f((Q).y, w##i1, a1); \
                            a2 = fdot2f((Q).z, w##i2, a2); a3 = fdot2f((Q).w, w##i3, a3); }
#define QDU(Q,i0,i1,i2,i3) { a0 = fdot2f((Q).x, u##i0, a0); a1 = fdot2f((Q).y, u##i1, a1); \
                             a2 = fdot2f((Q).z, u##i2, a2); a3 = fdot2f((Q).w, u##i3, a3); }

// ---------------- decoder (R18/R21 best-known: ~176 us; 256 blocks, DPP reduce) ----------------
__global__ __launch_bounds__(1024, 1)
void dec_kernel(const float* __restrict__ x,
                const float* __restrict__ Wih_f, const float* __restrict__ Whh_f, const float* __restrict__ b_f,
                const float* __restrict__ Wih_b, const float* __restrict__ Whh_b, const float* __restrict__ b_b,
                const float* __restrict__ Wlin, const float* __restrict__ blin,
                const float* __restrict__ st, float* __restrict__ out)
{
    __shared__ unsigned int hFh[NH / 2], hBh[NH / 2];
    __shared__ unsigned int inpH[NI / 2];
    __shared__ float g[1024];
    __shared__ float obuf[PRED * 16];    // 6KB output buffer, flushed once at end

    const int b    = blockIdx.x;
    const int t    = threadIdx.x;
    const int cell = t >> 9;
    const int r    = t & 511;
    const int w    = t >> 6;     // wave id = output index (16 waves, 16 outputs)
    const int ln   = t & 63;

    const float* Wih = cell ? Wih_b : Wih_f;
    const float* Whh = cell ? Whh_b : Whh_f;
    const float* bv  = cell ? b_b   : b_f;

#define DW(K) unsigned int w##K;
    R64(DW)
#undef DW
#define DU(K) unsigned int u##K;
    R8(DU)
#undef DU
    {
        const float* xr = Wih + r * NI;
        const float* hr = Whh + r * NH;
#define LU(K) u##K = packf16(xr[2*(K)], xr[2*(K)+1]);
        R8(LU)
#undef LU
#define LH(K) w##K = packf16(hr[2*(K)], hr[2*(K)+1]);
        R64(LH)
#undef LH
    }
    const float bias = bv[r];

    // out-projection statics: wave w, lane ln covers concat cols 4ln..4ln+3
    const float wl0 = Wlin[w * 256 + ln * 4 + 0];
    const float wl1 = Wlin[w * 256 + ln * 4 + 1];
    const float wl2 = Wlin[w * 256 + ln * 4 + 2];
    const float wl3 = Wlin[w * 256 + ln * 4 + 3];
    const float blw = blin[w];

    float cc = 0.0f;
    if (t < 64) {
        const float* sh = st + ((b * 2 + 0) * 2 + 0) * NH;
        hFh[t] = packf16(sh[2 * t], sh[2 * t + 1]);
    } else if (t < 128) {
        const float* sh = st + ((b * 2 + 1) * 2 + 0) * NH;
        hBh[t - 64] = packf16(sh[2 * (t - 64)], sh[2 * (t - 64) + 1]);
    }
    if (t < NH) cc = st[((b * 2 + 0) * 2 + 1) * NH + t];
    else if (t >= 512 && t < 512 + NH) cc = st[((b * 2 + 1) * 2 + 1) * NH + (t - 512)];
    if (t < 8) {
        float2 v = ((const float2*)(x + (size_t)b * TB * NI + (TB - 1) * NI))[t];
        inpH[t] = packf16(v.x, v.y);
    }
    __syncthreads();

    for (int s = 0; s < PRED; ++s) {
        // ---- P1: gates ----
        float a0 = bias, a1 = 0.f, a2 = 0.f, a3 = 0.f;
        uint4 q;
        {
            const uint4* xv = (const uint4*)inpH;
            q = xv[0]; QDU(q, 0, 1, 2, 3)
            q = xv[1]; QDU(q, 4, 5, 6, 7)
        }
        const uint4* hv = cell ? (const uint4*)hBh : (const uint4*)hFh;
        q = hv[0];  QD(q, 0, 1, 2, 3)
        q = hv[1];  QD(q, 4, 5, 6, 7)
        q = hv[2];  QD(q, 8, 9, 10, 11)
        q = hv[3];  QD(q, 12, 13, 14, 15)
        q = hv[4];  QD(q, 16, 17, 18, 19)
        q = hv[5];  QD(q, 20, 21, 22, 23)
        q = hv[6];  QD(q, 24, 25, 26, 27)
        q = hv[7];  QD(q, 28, 29, 30, 31)
        q = hv[8];  QD(q, 32, 33, 34, 35)
        q = hv[9];  QD(q, 36, 37, 38, 39)
        q = hv[10]; QD(q, 40, 41, 42, 43)
        q = hv[11]; QD(q, 44, 45, 46, 47)
        q = hv[12]; QD(q, 48, 49, 50, 51)
        q = hv[13]; QD(q, 52, 53, 54, 55)
        q = hv[14]; QD(q, 56, 57, 58, 59)
        q = hv[15]; QD(q, 60, 61, 62, 63)
        g[t] = (a0 + a1) + (a2 + a3);
        __syncthreads();

        // ---- P2: cell update ----
        if ((t < NH) || (t >= 512 && t < 512 + NH)) {
            float gi = g[t], gf = g[t + NH], gg = g[t + 2 * NH], go = g[t + 3 * NH];
            cc = sigf(gf) * cc + sigf(gi) * tanhf_(gg);
            float h = sigf(go) * tanhf_(cc);
            if (t < NH) ((_Float16*)hFh)[t] = (_Float16)h;
            else        ((_Float16*)hBh)[t - 512] = (_Float16)h;
        }
        __syncthreads();

        // ---- P3: out[w] = concat(hF,hB).Wlin[w] + blin[w]; DPP reduce -> lane 63
        {
            const unsigned int* hsrc = (ln < 32) ? (hFh + 2 * ln) : (hBh + 2 * (ln - 32));
            uint2 hw = *(const uint2*)hsrc;
            float2 va = unpackf16(hw.x), vb = unpackf16(hw.y);
            float p = va.x * wl0 + va.y * wl1 + vb.x * wl2 + vb.y * wl3;
            p = dppadd<0x111, 0xf>(p);   // row_shr:1
            p = dppadd<0x112, 0xf>(p);   // row_shr:2
            p = dppadd<0x114, 0xf>(p);   // row_shr:4
            p = dppadd<0x118, 0xf>(p);   // row_shr:8  -> lane 15/31/47/63 = row sums
            p = dppadd<0x142, 0xa>(p);   // row_bcast15 -> rows 1,3
            p = dppadd<0x143, 0xc>(p);   // row_bcast31 -> rows 2,3; total @ lane 63
            if (ln == 63) {
                float o = p + blw;
                obuf[s * NI + w] = o;
                ((_Float16*)inpH)[w] = (_Float16)o;
            }
        }
        __syncthreads();
    }

    // flush outputs once (coalesced float4)
    {
        float4* dst = (float4*)(out + (size_t)b * PRED * NI);
        const float4* src = (const float4*)obuf;
        for (int i = t; i < PRED * NI / 4; i += 1024) dst[i] = src[i];
    }
}

extern "C" void kernel_launch(void* const* d_in, const int* in_sizes, int n_in,
                              void* d_out, int out_size, void* d_ws, size_t ws_size,
                              hipStream_t stream)
{
    const float* x      = (const float*)d_in[0];
    const float* eWih_f = (const float*)d_in[1];
    const float* eWhh_f = (const float*)d_in[2];
    const float* eb_f   = (const float*)d_in[3];
    const float* eWih_b = (const float*)d_in[4];
    const float* eWhh_b = (const float*)d_in[5];
    const float* eb_b   = (const float*)d_in[6];
    const float* dWih_f = (const float*)d_in[7];
    const float* dWhh_f = (const float*)d_in[8];
    const float* db_f   = (const float*)d_in[9];
    const float* dWih_b = (const float*)d_in[10];
    const float* dWhh_b = (const float*)d_in[11];
    const float* db_b   = (const float*)d_in[12];
    const float* Wlin   = (const float*)d_in[13];
    const float* blin   = (const float*)d_in[14];

    float* st = (float*)d_ws;  // 256*2*2*128 f32 encoder final states

    enc_kernel<<<32, 1024, 0, stream>>>(x, eWih_f, eWhh_f, eb_f, eWih_b, eWhh_b, eb_b, st);
    dec_kernel<<<256, 1024, 0, stream>>>(x, dWih_f, dWhh_f, db_f, dWih_b, dWhh_b, db_b,
                                         Wlin, blin, st, (float*)d_out);
}